// Round 2
// baseline (7670.599 us; speedup 1.0000x reference)
//
#include <hip/hip_runtime.h>
#include <math.h>

// TransformerCell recurrence, 5 phases/step:
//   A: append d_{t-1}=B z_prev, U_{t-1}=W~ z_prev (B=W1@W2, W~=m_in_w@W3 precomposed,
//      held in registers of 64 main blocks); logits_i = d_i . z_prev (distributed),
//      per-block partials of logit_{t-1} -> lgp[64].
//   SM: softmax over logits (+ (257-t) zero rows) and f1 = lrelu(sum_i a_i U_i + m_in_b)
//   C:  f2 = lrelu(m_h0_w f1 + b)
//   D:  f3 = lrelu(m_h1_w f2 + b)
//   E:  z_t = z_prev + m_out_w f3 + m_out_b
// Prologue (256 blocks): P0 B/W~/p_in, P1 p_h0 (+reg load), P2 p_h1, P3 p_out->Z[0], z0->Z[1],
// P4 (64 blocks) append row 0. Custom monotonic 2-level LLC barriers (full=256, lite=64).
// Coherence rule: per-step-rewritten buffers (f1/f2/f3/lg/lgp) via agent-scope relaxed
// atomics (LLC, bypass L1/L2). Write-once-per-launch data (Z rows, d/U caches) via normal
// cached loads AFTER their barrier-ordered write; guarded by uniform branches (no
// speculative fills). Weights (d_in) always normal cached loads.

#define NTHR 256
#define NBLK 256
#define NMAIN 64

#define OFF_B   2048
#define OFF_W   (2048 + 1048576)
#define OFF_D   2048                 /* alias over B (B dead after reg-load) */
#define OFF_U   (2048 + 263168)      /* alias inside B region */
#define OFF_LG  (OFF_W + 1048576)    /* 257 */
#define OFF_LGP (OFF_LG + 320)       /* 64 */
#define OFF_F1  (OFF_LGP + 64)
#define OFF_F2  (OFF_F1 + 1024)
#define OFF_F3  (OFF_F2 + 1024)

__device__ __forceinline__ float aload(const float* p) {
  return __hip_atomic_load((float*)p, __ATOMIC_RELAXED, __HIP_MEMORY_SCOPE_AGENT);
}
__device__ __forceinline__ void astore(float* p, float v) {
  __hip_atomic_store(p, v, __ATOMIC_RELAXED, __HIP_MEMORY_SCOPE_AGENT);
}
__device__ __forceinline__ float2 aload2(const float* p) {
  double d = __hip_atomic_load((double*)p, __ATOMIC_RELAXED, __HIP_MEMORY_SCOPE_AGENT);
  return __builtin_bit_cast(float2, d);
}
__device__ __forceinline__ void astore2(float* p, float2 v) {
  __hip_atomic_store((double*)p, __builtin_bit_cast(double, v), __ATOMIC_RELAXED, __HIP_MEMORY_SCOPE_AGENT);
}
__device__ __forceinline__ int aloadI(const int* p) {
  return __hip_atomic_load((int*)p, __ATOMIC_RELAXED, __HIP_MEMORY_SCOPE_AGENT);
}
__device__ __forceinline__ void astoreI(int* p, int v) {
  __hip_atomic_store(p, v, __ATOMIC_RELAXED, __HIP_MEMORY_SCOPE_AGENT);
}
__device__ __forceinline__ int afaddI(int* p) {
  return __hip_atomic_fetch_add(p, 1, __ATOMIC_RELAXED, __HIP_MEMORY_SCOPE_AGENT);
}

__device__ __forceinline__ float wred(float v) {
#pragma unroll
  for (int o = 1; o < 64; o <<= 1) v += __shfl_xor(v, o, 64);
  return v;
}
__device__ __forceinline__ void wred2(float& a, float& b) {
#pragma unroll
  for (int o = 1; o < 64; o <<= 1) { a += __shfl_xor(a, o, 64); b += __shfl_xor(b, o, 64); }
}

// full barrier: 256 blocks, 32 groups of 8, 8 replicated release flags
__device__ __forceinline__ void barfull(int* bar, int k, int bid) {
  asm volatile("" ::: "memory");
  __builtin_amdgcn_s_waitcnt(0);
  __syncthreads();
  if (threadIdx.x == 0) {
    int g = bid >> 3;
    if (afaddI(&bar[g * 16]) == k * 8 + 7) {
      if (afaddI(&bar[512]) == k * 32 + 31) {
#pragma unroll
        for (int j = 0; j < 8; ++j) astoreI(&bar[528 + 16 * j], k + 1);
      }
    }
    while (aloadI(&bar[528 + 16 * (g & 7)]) <= k) {}
  }
  __syncthreads();
  asm volatile("" ::: "memory");
}
// lite barrier: 64 blocks, 8 groups of 8
__device__ __forceinline__ void barlite(int* bar, int k, int bid) {
  asm volatile("" ::: "memory");
  __builtin_amdgcn_s_waitcnt(0);
  __syncthreads();
  if (threadIdx.x == 0) {
    int g = bid >> 3;
    if (afaddI(&bar[768 + g * 16]) == k * 8 + 7) {
      if (afaddI(&bar[896]) == k * 8 + 7) {
#pragma unroll
        for (int j = 0; j < 8; ++j) astoreI(&bar[912 + 16 * j], k + 1);
      }
    }
    while (aloadI(&bar[912 + 16 * g]) <= k) {}
  }
  __syncthreads();
  asm volatile("" ::: "memory");
}

// prologue matvec: 1 row/wave (r = 4*bid+wave), K=1024, cached weights, aload x
template<int ACT>
__device__ __forceinline__ void mlrow1(const float* __restrict__ Wm, const float* __restrict__ bv,
                                       const float* xa, float* out, int bid, int wave, int lane) {
  float2 x[8];
#pragma unroll
  for (int i = 0; i < 8; ++i) x[i] = aload2(xa + 2 * lane + 128 * i);
  int r = 4 * bid + wave;
  const float* w = Wm + (size_t)r * 1024;
  float acc = 0.f;
#pragma unroll
  for (int i = 0; i < 8; ++i) {
    float2 wf = *(const float2*)(w + 2 * lane + 128 * i);
    acc = fmaf(wf.x, x[i].x, acc); acc = fmaf(wf.y, x[i].y, acc);
  }
  acc = wred(acc);
  if (lane == 0) {
    acc += bv[r];
    if (ACT) acc = acc > 0.f ? acc : 0.01f * acc;
    astore(out + r, acc);
  }
}

// main matvec: 4 rows/wave (r = 16*bid+4*wave+j), K=1024
template<int ACT>
__device__ __forceinline__ void mlrow4(const float* __restrict__ Wm, const float* __restrict__ bv,
                                       const float* xa, float* out, int bid, int wave, int lane) {
  float2 x[8];
#pragma unroll
  for (int i = 0; i < 8; ++i) x[i] = aload2(xa + 2 * lane + 128 * i);
#pragma unroll
  for (int j = 0; j < 4; ++j) {
    int r = 16 * bid + 4 * wave + j;
    const float* w = Wm + (size_t)r * 1024;
    float acc = 0.f;
#pragma unroll
    for (int i = 0; i < 8; ++i) {
      float2 wf = *(const float2*)(w + 2 * lane + 128 * i);
      acc = fmaf(wf.x, x[i].x, acc); acc = fmaf(wf.y, x[i].y, acc);
    }
    acc = wred(acc);
    if (lane == 0) {
      acc += bv[r];
      if (ACT) acc = acc > 0.f ? acc : 0.01f * acc;
      astore(out + r, acc);
    }
  }
}

__global__ void __launch_bounds__(NTHR, 1) tcell(
    const float* __restrict__ mu, const float* __restrict__ z0,
    const float* __restrict__ W1, const float* __restrict__ W2, const float* __restrict__ W3,
    const float* __restrict__ p_in_w, const float* __restrict__ p_in_b,
    const float* __restrict__ p_h0_w, const float* __restrict__ p_h0_b,
    const float* __restrict__ p_h1_w, const float* __restrict__ p_h1_b,
    const float* __restrict__ p_out_w, const float* __restrict__ p_out_b,
    const float* __restrict__ m_in_w, const float* __restrict__ m_in_b,
    const float* __restrict__ m_h0_w, const float* __restrict__ m_h0_b,
    const float* __restrict__ m_h1_w, const float* __restrict__ m_h1_b,
    const float* __restrict__ m_out_w, const float* __restrict__ m_out_b,
    float* __restrict__ Z, float* __restrict__ ws) {
  const int tid = threadIdx.x;
  const int bid = blockIdx.x;
  const int lane = tid & 63;
  const int wave = tid >> 6;

  int* bar = (int*)ws;
  float* dC = ws + OFF_D;
  float* uC = ws + OFF_U;
  float* lg = ws + OFF_LG;
  float* lgp = ws + OFF_LGP;
  float* f1 = ws + OFF_F1;
  float* f2 = ws + OFF_F2;
  float* f3 = ws + OFF_F3;

  __shared__ float shP[4];
  __shared__ float shQ[4][4];
  __shared__ float shM[4];
  __shared__ float shm0;
  __shared__ float shR[4][17];

  // ---- P0: B rows, W~ rows (4/block, 1/wave), p_in layer
  {
    int r = 4 * bid + wave;
    const float* w1r = W1 + (size_t)r * 512;
    const float* mir = m_in_w + (size_t)r * 512;
    float2 aB[8], aW[8];
#pragma unroll
    for (int i = 0; i < 8; ++i) { aB[i] = make_float2(0.f, 0.f); aW[i] = make_float2(0.f, 0.f); }
    for (int k = 0; k < 512; ++k) {
      float w1 = w1r[k], mi = mir[k];
      const float* w2r = W2 + (size_t)k * 1024 + 2 * lane;
      const float* w3r = W3 + (size_t)k * 1024 + 2 * lane;
#pragma unroll
      for (int i = 0; i < 8; ++i) {
        float2 a = *(const float2*)(w2r + 128 * i);
        float2 b = *(const float2*)(w3r + 128 * i);
        aB[i].x = fmaf(w1, a.x, aB[i].x); aB[i].y = fmaf(w1, a.y, aB[i].y);
        aW[i].x = fmaf(mi, b.x, aW[i].x); aW[i].y = fmaf(mi, b.y, aW[i].y);
      }
    }
#pragma unroll
    for (int i = 0; i < 8; ++i) {
      astore2(ws + OFF_B + (size_t)r * 1024 + 2 * lane + 128 * i, aB[i]);
      astore2(ws + OFF_W + (size_t)r * 1024 + 2 * lane + 128 * i, aW[i]);
    }
    // p_in: f1 = lrelu(p_in_w @ mu + b), K=64
    float acc = p_in_w[(size_t)r * 64 + lane] * mu[lane];
    acc = wred(acc);
    if (lane == 0) { acc += p_in_b[r]; acc = acc > 0.f ? acc : 0.01f * acc; astore(f1 + r, acc); }
  }
  barfull(bar, 0, bid);

  // ---- P1: f2 = lrelu(p_h0_w f1 + b); main blocks also load B/W~ rows to regs
  float2 rB[4][8], rW[4][8];
  if (bid < NMAIN) {
#pragma unroll
    for (int j = 0; j < 4; ++j) {
      int r = 16 * bid + 4 * wave + j;
#pragma unroll
      for (int i = 0; i < 8; ++i) {
        rB[j][i] = aload2(ws + OFF_B + (size_t)r * 1024 + 2 * lane + 128 * i);
        rW[j][i] = aload2(ws + OFF_W + (size_t)r * 1024 + 2 * lane + 128 * i);
      }
    }
  }
  mlrow1<1>(p_h0_w, p_h0_b, f1, f2, bid, wave, lane);
  barfull(bar, 1, bid);
  mlrow1<1>(p_h1_w, p_h1_b, f2, f3, bid, wave, lane);
  barfull(bar, 2, bid);
  // P3: Z[0] = p_out_w f3 + b (no act); Z[1] = z0
  mlrow1<0>(p_out_w, p_out_b, f3, Z, bid, wave, lane);
  if (bid < 4) astore(Z + 1024 + bid * 256 + tid, z0[bid * 256 + tid]);
  barfull(bar, 3, bid);

  if (bid >= NMAIN) return;

  // ---- P4: append row 0 (d_0, U_0 from Z[0])
  {
    float2 zp[8];
#pragma unroll
    for (int i = 0; i < 8; ++i) zp[i] = *(const float2*)(Z + 2 * lane + 128 * i);
#pragma unroll
    for (int j = 0; j < 4; ++j) {
      int r = 16 * bid + 4 * wave + j;
      float aD = 0.f, aU = 0.f;
#pragma unroll
      for (int i = 0; i < 8; ++i) {
        aD = fmaf(rB[j][i].x, zp[i].x, aD); aD = fmaf(rB[j][i].y, zp[i].y, aD);
        aU = fmaf(rW[j][i].x, zp[i].x, aU); aU = fmaf(rW[j][i].y, zp[i].y, aU);
      }
      wred2(aD, aU);
      if (lane == 0) { astore(dC + r, aD); astore(uC + r, aU); }
    }
  }
  int lk = 0;
  barlite(bar, lk++, bid);

  // ---- main recurrence
  for (int t = 2; t <= 256; ++t) {
    const float* zprev = Z + (size_t)(t - 1) * 1024;

    // Phase A: append d/U row t-1; logits for i<=t-2; partials for logit_{t-1}
    {
      float2 zp[8];
#pragma unroll
      for (int i = 0; i < 8; ++i) zp[i] = *(const float2*)(zprev + 2 * lane + 128 * i);
      float4 zq = *(const float4*)(zprev + 4 * tid);
      float4 dr[4]; int li[4]; bool vi[4];
#pragma unroll
      for (int j = 0; j < 4; ++j) {
        li[j] = bid + 64 * j; vi[j] = (li[j] <= t - 2);
        dr[j] = make_float4(0.f, 0.f, 0.f, 0.f);
        if (vi[j]) dr[j] = *(const float4*)(dC + (size_t)li[j] * 1024 + 4 * tid);
      }
      float* dRow = dC + (size_t)(t - 1) * 1024;
      float* uRow = uC + (size_t)(t - 1) * 1024;
      float pl = 0.f;
#pragma unroll
      for (int j = 0; j < 4; ++j) {
        int r = 16 * bid + 4 * wave + j;
        float aD = 0.f, aU = 0.f;
#pragma unroll
        for (int i = 0; i < 8; ++i) {
          aD = fmaf(rB[j][i].x, zp[i].x, aD); aD = fmaf(rB[j][i].y, zp[i].y, aD);
          aU = fmaf(rW[j][i].x, zp[i].x, aU); aU = fmaf(rW[j][i].y, zp[i].y, aU);
        }
        wred2(aD, aU);
        if (lane == 0) {
          astore(dRow + r, aD); astore(uRow + r, aU);
          pl = fmaf(aD, zprev[r], pl);
        }
      }
      if (lane == 0) shP[wave] = pl;
      float a4[4];
#pragma unroll
      for (int j = 0; j < 4; ++j)
        a4[j] = dr[j].x * zq.x + dr[j].y * zq.y + dr[j].z * zq.z + dr[j].w * zq.w;
#pragma unroll
      for (int o = 1; o < 64; o <<= 1) {
#pragma unroll
        for (int j = 0; j < 4; ++j) a4[j] += __shfl_xor(a4[j], o, 64);
      }
      if (lane == 0) {
#pragma unroll
        for (int j = 0; j < 4; ++j) shQ[wave][j] = a4[j];
      }
      __syncthreads();
      if (tid == 0) {
        astore(lgp + bid, shP[0] + shP[1] + shP[2] + shP[3]);
#pragma unroll
        for (int j = 0; j < 4; ++j)
          if (vi[j]) astore(lg + li[j], shQ[0][j] + shQ[1][j] + shQ[2][j] + shQ[3][j]);
      }
    }
    barlite(bar, lk++, bid);

    // Phase SM: softmax + f1 = lrelu(sum a_i U_i + m_in_b)
    {
      bool act = (tid < t);
      float4 uv[4];
#pragma unroll
      for (int j = 0; j < 4; ++j) {
        uv[j] = make_float4(0.f, 0.f, 0.f, 0.f);
        if (act) uv[j] = *(const float4*)(uC + (size_t)tid * 1024 + 16 * bid + 4 * j);
      }
      float lgv = (tid <= t - 2) ? aload(lg + tid) : 0.f;
      float lgpv = (tid < 64) ? aload(lgp + tid) : 0.f;
      if (wave == 0) {
        float s = lgpv;
#pragma unroll
        for (int o = 1; o < 64; o <<= 1) s += __shfl_xor(s, o, 64);
        if (lane == 0) shm0 = s;
      }
      __syncthreads();
      float l = act ? 0.03125f * ((tid == t - 1) ? shm0 : lgv) : -1e30f;
      float mx = l;
#pragma unroll
      for (int o = 1; o < 64; o <<= 1) mx = fmaxf(mx, __shfl_xor(mx, o, 64));
      if (lane == 0) shM[wave] = mx;
      __syncthreads();
      float m = fmaxf(fmaxf(fmaxf(shM[0], shM[1]), fmaxf(shM[2], shM[3])), 0.f);
      float e = act ? expf(l - m) : 0.f;
      float s17[17];
      s17[16] = e;
#pragma unroll
      for (int j = 0; j < 4; ++j) {
        s17[4 * j + 0] = e * uv[j].x; s17[4 * j + 1] = e * uv[j].y;
        s17[4 * j + 2] = e * uv[j].z; s17[4 * j + 3] = e * uv[j].w;
      }
#pragma unroll
      for (int o = 1; o < 64; o <<= 1) {
#pragma unroll
        for (int q = 0; q < 17; ++q) s17[q] += __shfl_xor(s17[q], o, 64);
      }
      if (lane == 0) {
#pragma unroll
        for (int q = 0; q < 17; ++q) shR[wave][q] = s17[q];
      }
      __syncthreads();
      if (tid < 16) {
        float s = shR[0][tid] + shR[1][tid] + shR[2][tid] + shR[3][tid];
        float den = shR[0][16] + shR[1][16] + shR[2][16] + shR[3][16]
                    + (float)(257 - t) * expf(-m);
        float v = s / den + m_in_b[16 * bid + tid];
        v = v > 0.f ? v : 0.01f * v;
        astore(f1 + 16 * bid + tid, v);
      }
    }
    barlite(bar, lk++, bid);

    // Phase C/D: hidden layers
    mlrow4<1>(m_h0_w, m_h0_b, f1, f2, bid, wave, lane);
    barlite(bar, lk++, bid);
    mlrow4<1>(m_h1_w, m_h1_b, f2, f3, bid, wave, lane);
    barlite(bar, lk++, bid);

    // Phase E: z_t = z_prev + m_out_w f3 + m_out_b
    {
      float2 x[8];
#pragma unroll
      for (int i = 0; i < 8; ++i) x[i] = aload2(f3 + 2 * lane + 128 * i);
#pragma unroll
      for (int j = 0; j < 4; ++j) {
        int r = 16 * bid + 4 * wave + j;
        const float* w = m_out_w + (size_t)r * 1024;
        float acc = 0.f;
#pragma unroll
        for (int i = 0; i < 8; ++i) {
          float2 wf = *(const float2*)(w + 2 * lane + 128 * i);
          acc = fmaf(wf.x, x[i].x, acc); acc = fmaf(wf.y, x[i].y, acc);
        }
        acc = wred(acc);
        if (lane == 0) astore(Z + (size_t)t * 1024 + r, acc + m_out_b[r] + zprev[r]);
      }
    }
    barlite(bar, lk++, bid);
  }
}

extern "C" void kernel_launch(void* const* d_in, const int* in_sizes, int n_in,
                              void* d_out, int out_size, void* d_ws, size_t ws_size,
                              hipStream_t stream) {
  (void)in_sizes; (void)n_in; (void)out_size; (void)ws_size;
  hipMemsetAsync(d_ws, 0, 8192, stream);  // barrier counters
  tcell<<<dim3(NBLK), dim3(NTHR), 0, stream>>>(
      (const float*)d_in[0],  (const float*)d_in[1],
      (const float*)d_in[2],  (const float*)d_in[3],  (const float*)d_in[4],
      (const float*)d_in[5],  (const float*)d_in[6],
      (const float*)d_in[7],  (const float*)d_in[8],
      (const float*)d_in[9],  (const float*)d_in[10],
      (const float*)d_in[11], (const float*)d_in[12],
      (const float*)d_in[13], (const float*)d_in[14],
      (const float*)d_in[15], (const float*)d_in[16],
      (const float*)d_in[17], (const float*)d_in[18],
      (const float*)d_in[19], (const float*)d_in[20],
      (float*)d_out, (float*)d_ws);
}